// Round 10
// baseline (3414.116 us; speedup 1.0000x reference)
//
#include <hip/hip_runtime.h>
#include <math.h>

#define BATCH   512
#define N       128
#define DDIM    1024
#define NITER   30
#define NCG     24
#define SIGMA_C 0.1f
#define EPS_C   1e-6f
#define MPAD    132

// ---------------- Kernel A: Q = 2*(X X^T + eps I) ----------------
__global__ __launch_bounds__(256) void gram_kernel(const float* __restrict__ X,
                                                   float* __restrict__ Q) {
    const int b = blockIdx.x;
    const float* Xb = X + (size_t)b * N * DDIM;
    float* Qb = Q + (size_t)b * N * N;

    __shared__ float Xs[16][MPAD];
    const int t  = threadIdx.x;
    const int tx = t & 15, ty = t >> 4;
    const int li = t >> 1;
    const int lk = (t & 1) * 8;

    float acc[8][8];
#pragma unroll
    for (int u = 0; u < 8; ++u)
#pragma unroll
        for (int v = 0; v < 8; ++v) acc[u][v] = 0.0f;

    for (int k0 = 0; k0 < DDIM; k0 += 16) {
        const float4 p0 = *(const float4*)(Xb + (size_t)li * DDIM + k0 + lk);
        const float4 p1 = *(const float4*)(Xb + (size_t)li * DDIM + k0 + lk + 4);
        __syncthreads();
        Xs[lk + 0][li] = p0.x; Xs[lk + 1][li] = p0.y;
        Xs[lk + 2][li] = p0.z; Xs[lk + 3][li] = p0.w;
        Xs[lk + 4][li] = p1.x; Xs[lk + 5][li] = p1.y;
        Xs[lk + 6][li] = p1.z; Xs[lk + 7][li] = p1.w;
        __syncthreads();
#pragma unroll
        for (int kk = 0; kk < 16; ++kk) {
            float4 A0 = *(const float4*)&Xs[kk][ty * 8];
            float4 A1 = *(const float4*)&Xs[kk][ty * 8 + 4];
            float4 C0 = *(const float4*)&Xs[kk][tx * 8];
            float4 C1 = *(const float4*)&Xs[kk][tx * 8 + 4];
            float a[8] = {A0.x, A0.y, A0.z, A0.w, A1.x, A1.y, A1.z, A1.w};
            float c[8] = {C0.x, C0.y, C0.z, C0.w, C1.x, C1.y, C1.z, C1.w};
#pragma unroll
            for (int u = 0; u < 8; ++u)
#pragma unroll
                for (int v = 0; v < 8; ++v) acc[u][v] += a[u] * c[v];
        }
    }
#pragma unroll
    for (int u = 0; u < 8; ++u) {
        const int i = ty * 8 + u;
#pragma unroll
        for (int v = 0; v < 8; ++v) {
            const int k = tx * 8 + v;
            acc[u][v] = 2.0f * acc[u][v] + ((i == k) ? 2.0f * EPS_C : 0.0f);
        }
        float4 o0, o1;
        o0.x = acc[u][0]; o0.y = acc[u][1]; o0.z = acc[u][2]; o0.w = acc[u][3];
        o1.x = acc[u][4]; o1.y = acc[u][5]; o1.z = acc[u][6]; o1.w = acc[u][7];
        *(float4*)(Qb + (size_t)i * N + tx * 8)     = o0;
        *(float4*)(Qb + (size_t)i * N + tx * 8 + 4) = o1;
    }
}

// ---------------- Kernel B: IPM + dual Jacobi-PCG, Q register-resident ----------------
// 256 threads: thread t owns row r=t>>1, column half h=t&1 (64 floats of Q in
// 16 float4 VGPRs, loaded once). Matvec = LDS broadcast-read of u (2 uniform
// addresses per wave -> 2-way, free) x register Q + one shfl_xor(1) to join
// halves (adjacent lanes hold the two halves of the same row). CG state in
// registers, pair-duplicated; reductions use the x0.5 duplicated-sum trick.
// RACE FIX vs r9: in P1, ALL threads read u0/u1 (holding warm-start x) for the
// matvec; the overwrite u0[r]=uu0 must wait for every wave's reads -> barrier
// B1b between residual computation and the u-write.
__global__ __launch_bounds__(256) void ipm_cg(const float* __restrict__ Q,
                                              float* __restrict__ alphas) {
    __shared__ __align__(16) float u0[N], u1[N], avl[N];
    __shared__ float scal[32];
    // scal: [0..3] sum_a | sx0   [4..7] sum_al | sx1
    //       [8..15] gamma buf A (g0:8-11, g1:12-15)
    //       [16..19] delta0 | rmin   [20..23] delta1
    //       [24..31] gamma buf B (g0:24-27, g1:28-31)

    const int t    = threadIdx.x;
    const int lane = t & 63;
    const int w    = t >> 6;
    const int r    = t >> 1;       // owned row
    const int h    = t & 1;        // column half
    const int b    = blockIdx.x;
    const float* Qb = Q + (size_t)b * N * N;

    // ---- one-time Q half-row load into registers ----
    float4 Rq[16];
    {
        const float* src = Qb + (size_t)r * N + (h << 6);
#pragma unroll
        for (int s = 0; s < 16; ++s) Rq[s] = *(const float4*)(src + (s << 2));
    }
    const float qd = Qb[(size_t)r * N + r];
    const float pp = -0.5f * qd;
    float avr = 1.0f / 128.0f, lmr = 1.0f;
    float x0 = 0.0f, x1 = 0.0f;          // warm-start solutions
    float nu = 0.0f;
    if (h == 0) avl[r] = avr;
    __syncthreads();

#pragma unroll 1
    for (int iter = 0; iter < NITER; ++iter) {
        // ---- P0: qa = Q@a (register matvec); stats; u := x ----
        float qa;
        {
            const float4* A4 = (const float4*)&avl[h << 6];
            float s0 = 0.0f;
#pragma unroll
            for (int s = 0; s < 16; ++s) {
                const float4 q = Rq[s], a = A4[s];
                s0 = fmaf(q.x, a.x, s0); s0 = fmaf(q.y, a.y, s0);
                s0 = fmaf(q.z, a.z, s0); s0 = fmaf(q.w, a.w, s0);
            }
            qa = s0 + __shfl_xor(s0, 1);
        }
        if (h == 0) { u0[r] = x0; u1[r] = x1; }
        {
            float sa = avr, sal = avr * lmr;
#pragma unroll
            for (int o = 32; o; o >>= 1) { sa += __shfl_xor(sa, o); sal += __shfl_xor(sal, o); }
            if (lane == 0) { scal[0 + w] = 0.5f * sa; scal[4 + w] = 0.5f * sal; }
        }
        __syncthreads();                                    // B1

        // ---- P1: warm matvec A*x; residual; first direction; gamma0 ----
        const float r_pri = scal[0] + scal[1] + scal[2] + scal[3] - 1.0f;
        const float mu    = (scal[4] + scal[5] + scal[6] + scal[7]) * (1.0f / 128.0f);
        const float ds    = lmr / avr;
        const float dinv  = 1.0f / (qd + ds);
        const float rhs0  = -(qa + pp + nu - SIGMA_C * mu / avr);
        float r0, r1, uu0, uu1;
        {
            const float4* U0 = (const float4*)&u0[h << 6];
            const float4* U1 = (const float4*)&u1[h << 6];
            float s0 = 0.0f, s1 = 0.0f;
#pragma unroll
            for (int s = 0; s < 16; ++s) {
                const float4 q = Rq[s];
                const float4 a = U0[s], c = U1[s];
                s0 = fmaf(q.x, a.x, s0); s0 = fmaf(q.y, a.y, s0);
                s0 = fmaf(q.z, a.z, s0); s0 = fmaf(q.w, a.w, s0);
                s1 = fmaf(q.x, c.x, s1); s1 = fmaf(q.y, c.y, s1);
                s1 = fmaf(q.z, c.z, s1); s1 = fmaf(q.w, c.w, s1);
            }
            const float ax0 = s0 + __shfl_xor(s0, 1) + ds * x0;
            const float ax1 = s1 + __shfl_xor(s1, 1) + ds * x1;
            r0 = rhs0 - ax0;
            r1 = 1.0f - ax1;
            uu0 = dinv * r0; uu1 = dinv * r1;
        }
        __syncthreads();                                    // B1b (race fix: drain x-reads)
        if (h == 0) { u0[r] = uu0; u1[r] = uu1; }
        {
            float g0 = r0 * uu0, g1 = r1 * uu1;
#pragma unroll
            for (int o = 32; o; o >>= 1) { g0 += __shfl_xor(g0, o); g1 += __shfl_xor(g1, o); }
            if (lane == 0) { scal[8 + w] = 0.5f * g0; scal[12 + w] = 0.5f * g1; }
        }
        __syncthreads();                                    // B2

        // ---- CG loop: 1 register matvec + 2 barriers per step ----
        float p0r = 0.0f, p1r = 0.0f, s0r = 0.0f, s1r = 0.0f;
        float g0old = 0.0f, g1old = 0.0f, a0old = 1.0f, a1old = 1.0f;
#pragma unroll 1
        for (int k = 0; k < NCG; ++k) {
            const int gb = (k & 1) ? 24 : 8;      // gamma buffer this step
            const int gn = (k & 1) ? 8 : 24;      // gamma buffer next step
            // S1: matvec w = A u (registers + LDS broadcast); delta partials
            float w0, w1;
            {
                const float4* U0 = (const float4*)&u0[h << 6];
                const float4* U1 = (const float4*)&u1[h << 6];
                float s0 = 0.0f, s1 = 0.0f;
#pragma unroll
                for (int s = 0; s < 16; ++s) {
                    const float4 q = Rq[s];
                    const float4 a = U0[s], c = U1[s];
                    s0 = fmaf(q.x, a.x, s0); s0 = fmaf(q.y, a.y, s0);
                    s0 = fmaf(q.z, a.z, s0); s0 = fmaf(q.w, a.w, s0);
                    s1 = fmaf(q.x, c.x, s1); s1 = fmaf(q.y, c.y, s1);
                    s1 = fmaf(q.z, c.z, s1); s1 = fmaf(q.w, c.w, s1);
                }
                w0 = s0 + __shfl_xor(s0, 1) + ds * uu0;
                w1 = s1 + __shfl_xor(s1, 1) + ds * uu1;
            }
            {
                float d0 = uu0 * w0, d1 = uu1 * w1;
#pragma unroll
                for (int o = 32; o; o >>= 1) { d0 += __shfl_xor(d0, o); d1 += __shfl_xor(d1, o); }
                if (lane == 0) { scal[16 + w] = 0.5f * d0; scal[20 + w] = 0.5f * d1; }
            }
            __syncthreads();                                // BA
            // S2: uniform alpha/beta; update state; next gamma partials
            // (u-write here is safe: S1's u-reads drained by BA; next reads after BB)
            {
                const float g0 = scal[gb] + scal[gb + 1] + scal[gb + 2] + scal[gb + 3];
                const float g1 = scal[gb + 4] + scal[gb + 5] + scal[gb + 6] + scal[gb + 7];
                const float d0 = scal[16] + scal[17] + scal[18] + scal[19];
                const float d1 = scal[20] + scal[21] + scal[22] + scal[23];
                float be0, be1, al0, al1;
                if (k == 0) {
                    be0 = 0.0f; be1 = 0.0f;
                    al0 = (g0 > 1e-30f) ? g0 / d0 : 0.0f;
                    al1 = (g1 > 1e-30f) ? g1 / d1 : 0.0f;
                } else {
                    be0 = (g0old > 1e-30f) ? g0 / g0old : 0.0f;
                    be1 = (g1old > 1e-30f) ? g1 / g1old : 0.0f;
                    const float den0 = d0 - be0 * g0 / a0old;
                    const float den1 = d1 - be1 * g1 / a1old;
                    al0 = (g0 > 1e-30f && den0 > 1e-30f) ? g0 / den0 : 0.0f;
                    al1 = (g1 > 1e-30f && den1 > 1e-30f) ? g1 / den1 : 0.0f;
                }
                g0old = g0; g1old = g1;
                a0old = (al0 != 0.0f) ? al0 : 1.0f;
                a1old = (al1 != 0.0f) ? al1 : 1.0f;
                p0r = uu0 + be0 * p0r;  s0r = w0 + be0 * s0r;
                p1r = uu1 + be1 * p1r;  s1r = w1 + be1 * s1r;
                x0 += al0 * p0r;        r0 -= al0 * s0r;
                x1 += al1 * p1r;        r1 -= al1 * s1r;
                uu0 = dinv * r0;        uu1 = dinv * r1;
                if (h == 0) { u0[r] = uu0; u1[r] = uu1; }
                float ng0 = r0 * uu0, ng1 = r1 * uu1;
#pragma unroll
                for (int o = 32; o; o >>= 1) { ng0 += __shfl_xor(ng0, o); ng1 += __shfl_xor(ng1, o); }
                if (lane == 0) { scal[gn + w] = 0.5f * ng0; scal[gn + 4 + w] = 0.5f * ng1; }
            }
            __syncthreads();                                // BB
        }

        // ---- epilogue: dnu, step length, update ----
        {
            float sx0 = x0, sx1 = x1;
#pragma unroll
            for (int o = 32; o; o >>= 1) { sx0 += __shfl_xor(sx0, o); sx1 += __shfl_xor(sx1, o); }
            if (lane == 0) { scal[0 + w] = 0.5f * sx0; scal[4 + w] = 0.5f * sx1; }
        }
        __syncthreads();                                    // B4
        const float dnu = (scal[0] + scal[1] + scal[2] + scal[3] + r_pri)
                        / (scal[4] + scal[5] + scal[6] + scal[7]);
        const float da = x0 - dnu * x1;
        const float dl = -lmr + SIGMA_C * mu / avr - lmr * da / avr;
        {
            float rmin = 3.4e38f;
            if (da < 0.0f) rmin = fminf(rmin, -avr / da);
            if (dl < 0.0f) rmin = fminf(rmin, -lmr / dl);
#pragma unroll
            for (int o = 32; o; o >>= 1) rmin = fminf(rmin, __shfl_xor(rmin, o));
            if (lane == 0) scal[16 + w] = rmin;
        }
        __syncthreads();                                    // B5
        const float ts = fminf(1.0f, 0.99f * fminf(fminf(scal[16], scal[17]),
                                                   fminf(scal[18], scal[19])));
        nu  += ts * dnu;
        avr += ts * da;
        lmr += ts * dl;
        if (h == 0) avl[r] = avr;
        __syncthreads();                                    // B6
    }

    if (h == 0) alphas[(size_t)b * N + r] = avr;
}

// ---------------- Kernel C: centers = alpha^T X ----------------
__global__ __launch_bounds__(256) void centers_kernel(const float* __restrict__ X,
                                                      const float* __restrict__ alphas,
                                                      float* __restrict__ out) {
    const int b = blockIdx.x;
    __shared__ float al[N];
    const int t = threadIdx.x;
    if (t < N) al[t] = alphas[(size_t)b * N + t];
    __syncthreads();
    const float* Xb = X + (size_t)b * N * DDIM;
    float acc0 = 0.0f, acc1 = 0.0f, acc2 = 0.0f, acc3 = 0.0f;
    for (int s = 0; s < N; ++s) {
        const float a = al[s];
        const float* row = Xb + (size_t)s * DDIM + t;
        acc0 += a * row[0];
        acc1 += a * row[256];
        acc2 += a * row[512];
        acc3 += a * row[768];
    }
    float* ob = out + (size_t)b * DDIM + t;
    ob[0]   = acc0;
    ob[256] = acc1;
    ob[512] = acc2;
    ob[768] = acc3;
}

extern "C" void kernel_launch(void* const* d_in, const int* in_sizes, int n_in,
                              void* d_out, int out_size, void* d_ws, size_t ws_size,
                              hipStream_t stream) {
    (void)in_sizes; (void)n_in; (void)out_size; (void)ws_size;
    const float* X = (const float*)d_in[0];
    float* out = (float*)d_out;
    float* Q = (float*)d_ws;                       // 512*128*128 f32 = 32 MB
    float* alphas = Q + (size_t)BATCH * N * N;     // + 256 KB
    gram_kernel<<<dim3(BATCH), dim3(256), 0, stream>>>(X, Q);
    ipm_cg<<<dim3(BATCH), dim3(256), 0, stream>>>(Q, alphas);
    centers_kernel<<<dim3(BATCH), dim3(256), 0, stream>>>(X, alphas, out);
}

// Round 11
// 1937.753 us; speedup vs baseline: 1.7619x; 1.7619x over previous
//
#include <hip/hip_runtime.h>
#include <math.h>

#define BATCH   512
#define N       128
#define DDIM    1024
#define NITER   30
#define NCG     24
#define SIGMA_C 0.1f
#define EPS_C   1e-6f
#define MPAD    132
#define HOFF    68    // half-vector stride: 68 mod 8 = 4 -> the two broadcast
                      // addresses of a wave hit DISJOINT 4-bank groups

// ---------------- Kernel A: Q = 2*(X X^T + eps I) ----------------
__global__ __launch_bounds__(256) void gram_kernel(const float* __restrict__ X,
                                                   float* __restrict__ Q) {
    const int b = blockIdx.x;
    const float* Xb = X + (size_t)b * N * DDIM;
    float* Qb = Q + (size_t)b * N * N;

    __shared__ float Xs[16][MPAD];
    const int t  = threadIdx.x;
    const int tx = t & 15, ty = t >> 4;
    const int li = t >> 1;
    const int lk = (t & 1) * 8;

    float acc[8][8];
#pragma unroll
    for (int u = 0; u < 8; ++u)
#pragma unroll
        for (int v = 0; v < 8; ++v) acc[u][v] = 0.0f;

    for (int k0 = 0; k0 < DDIM; k0 += 16) {
        const float4 p0 = *(const float4*)(Xb + (size_t)li * DDIM + k0 + lk);
        const float4 p1 = *(const float4*)(Xb + (size_t)li * DDIM + k0 + lk + 4);
        __syncthreads();
        Xs[lk + 0][li] = p0.x; Xs[lk + 1][li] = p0.y;
        Xs[lk + 2][li] = p0.z; Xs[lk + 3][li] = p0.w;
        Xs[lk + 4][li] = p1.x; Xs[lk + 5][li] = p1.y;
        Xs[lk + 6][li] = p1.z; Xs[lk + 7][li] = p1.w;
        __syncthreads();
#pragma unroll
        for (int kk = 0; kk < 16; ++kk) {
            float4 A0 = *(const float4*)&Xs[kk][ty * 8];
            float4 A1 = *(const float4*)&Xs[kk][ty * 8 + 4];
            float4 C0 = *(const float4*)&Xs[kk][tx * 8];
            float4 C1 = *(const float4*)&Xs[kk][tx * 8 + 4];
            float a[8] = {A0.x, A0.y, A0.z, A0.w, A1.x, A1.y, A1.z, A1.w};
            float c[8] = {C0.x, C0.y, C0.z, C0.w, C1.x, C1.y, C1.z, C1.w};
#pragma unroll
            for (int u = 0; u < 8; ++u)
#pragma unroll
                for (int v = 0; v < 8; ++v) acc[u][v] += a[u] * c[v];
        }
    }
#pragma unroll
    for (int u = 0; u < 8; ++u) {
        const int i = ty * 8 + u;
#pragma unroll
        for (int v = 0; v < 8; ++v) {
            const int k = tx * 8 + v;
            acc[u][v] = 2.0f * acc[u][v] + ((i == k) ? 2.0f * EPS_C : 0.0f);
        }
        float4 o0, o1;
        o0.x = acc[u][0]; o0.y = acc[u][1]; o0.z = acc[u][2]; o0.w = acc[u][3];
        o1.x = acc[u][4]; o1.y = acc[u][5]; o1.z = acc[u][6]; o1.w = acc[u][7];
        *(float4*)(Qb + (size_t)i * N + tx * 8)     = o0;
        *(float4*)(Qb + (size_t)i * N + tx * 8 + 4) = o1;
    }
}

// ---------------- Kernel B: IPM + dual Jacobi-PCG, Q register-resident ----------------
// Thread t owns row r=t>>1, column half h=t&1 (16 float4 of Q in VGPRs).
// Matvec: LDS broadcast-read of u x register Q + shfl_xor(1) half-join.
// vs r10: (a) __launch_bounds__(256,2) caps VGPR at 128 (r10's 132 crossed the
// 128 occupancy cliff -> 1 block/CU); (b) u0/u1/avl halves stored at stride 68
// so a wave's two broadcast addresses hit disjoint bank groups (r10: same banks,
// 3.8e8 conflict cycles).
__global__ __launch_bounds__(256, 2) void ipm_cg(const float* __restrict__ Q,
                                                 float* __restrict__ alphas) {
    __shared__ __align__(16) float u0[2 * HOFF], u1[2 * HOFF], avl[2 * HOFF];
    __shared__ float scal[32];
    // scal: [0..3] sum_a | sx0   [4..7] sum_al | sx1
    //       [8..15] gamma buf A (g0:8-11, g1:12-15)
    //       [16..19] delta0 | rmin   [20..23] delta1
    //       [24..31] gamma buf B (g0:24-27, g1:28-31)

    const int t    = threadIdx.x;
    const int lane = t & 63;
    const int w    = t >> 6;
    const int r    = t >> 1;                      // owned row
    const int h    = t & 1;                       // column half
    const int wr   = r + ((r >> 6) << 2);         // padded write index for row r
    const int b    = blockIdx.x;
    const float* Qb = Q + (size_t)b * N * N;

    // ---- one-time Q half-row load into registers ----
    float4 Rq[16];
    {
        const float* src = Qb + (size_t)r * N + (h << 6);
#pragma unroll
        for (int s = 0; s < 16; ++s) Rq[s] = *(const float4*)(src + (s << 2));
    }
    const float qd = Qb[(size_t)r * N + r];
    float avr = 1.0f / 128.0f, lmr = 1.0f;
    float x0 = 0.0f, x1 = 0.0f;          // warm-start solutions
    float nu = 0.0f;
    if (h == 0) avl[wr] = avr;
    __syncthreads();

#pragma unroll 1
    for (int iter = 0; iter < NITER; ++iter) {
        // ---- P0: qa = Q@a (register matvec); stats; u := x ----
        float qa;
        {
            const float4* A4 = (const float4*)&avl[h * HOFF];
            float s0 = 0.0f;
#pragma unroll
            for (int s = 0; s < 16; ++s) {
                const float4 q = Rq[s], a = A4[s];
                s0 = fmaf(q.x, a.x, s0); s0 = fmaf(q.y, a.y, s0);
                s0 = fmaf(q.z, a.z, s0); s0 = fmaf(q.w, a.w, s0);
            }
            qa = s0 + __shfl_xor(s0, 1);
        }
        if (h == 0) { u0[wr] = x0; u1[wr] = x1; }
        {
            float sa = avr, sal = avr * lmr;
#pragma unroll
            for (int o = 32; o; o >>= 1) { sa += __shfl_xor(sa, o); sal += __shfl_xor(sal, o); }
            if (lane == 0) { scal[0 + w] = 0.5f * sa; scal[4 + w] = 0.5f * sal; }
        }
        __syncthreads();                                    // B1

        // ---- P1: warm matvec A*x; residual; first direction; gamma0 ----
        const float r_pri = scal[0] + scal[1] + scal[2] + scal[3] - 1.0f;
        const float mu    = (scal[4] + scal[5] + scal[6] + scal[7]) * (1.0f / 128.0f);
        const float ds    = lmr / avr;
        const float dinv  = 1.0f / (qd + ds);
        const float rhs0  = -(qa - 0.5f * qd + nu - SIGMA_C * mu / avr);
        float r0, r1, uu0, uu1;
        {
            const float4* U0 = (const float4*)&u0[h * HOFF];
            const float4* U1 = (const float4*)&u1[h * HOFF];
            float s0 = 0.0f, s1 = 0.0f;
#pragma unroll
            for (int s = 0; s < 16; ++s) {
                const float4 q = Rq[s];
                const float4 a = U0[s], c = U1[s];
                s0 = fmaf(q.x, a.x, s0); s0 = fmaf(q.y, a.y, s0);
                s0 = fmaf(q.z, a.z, s0); s0 = fmaf(q.w, a.w, s0);
                s1 = fmaf(q.x, c.x, s1); s1 = fmaf(q.y, c.y, s1);
                s1 = fmaf(q.z, c.z, s1); s1 = fmaf(q.w, c.w, s1);
            }
            const float ax0 = s0 + __shfl_xor(s0, 1) + ds * x0;
            const float ax1 = s1 + __shfl_xor(s1, 1) + ds * x1;
            r0 = rhs0 - ax0;
            r1 = 1.0f - ax1;
            uu0 = dinv * r0; uu1 = dinv * r1;
        }
        __syncthreads();                                    // B1b (drain x-reads)
        if (h == 0) { u0[wr] = uu0; u1[wr] = uu1; }
        {
            float g0 = r0 * uu0, g1 = r1 * uu1;
#pragma unroll
            for (int o = 32; o; o >>= 1) { g0 += __shfl_xor(g0, o); g1 += __shfl_xor(g1, o); }
            if (lane == 0) { scal[8 + w] = 0.5f * g0; scal[12 + w] = 0.5f * g1; }
        }
        __syncthreads();                                    // B2

        // ---- CG loop: 1 register matvec + 2 barriers per step ----
        float p0r = 0.0f, p1r = 0.0f, s0r = 0.0f, s1r = 0.0f;
        float g0old = 0.0f, g1old = 0.0f, a0old = 1.0f, a1old = 1.0f;
#pragma unroll 1
        for (int k = 0; k < NCG; ++k) {
            const int gb = (k & 1) ? 24 : 8;      // gamma buffer this step
            const int gn = (k & 1) ? 8 : 24;      // gamma buffer next step
            // S1: matvec w = A u (registers + LDS broadcast); delta partials
            float w0, w1;
            {
                const float4* U0 = (const float4*)&u0[h * HOFF];
                const float4* U1 = (const float4*)&u1[h * HOFF];
                float s0 = 0.0f, s1 = 0.0f;
#pragma unroll
                for (int s = 0; s < 16; ++s) {
                    const float4 q = Rq[s];
                    const float4 a = U0[s], c = U1[s];
                    s0 = fmaf(q.x, a.x, s0); s0 = fmaf(q.y, a.y, s0);
                    s0 = fmaf(q.z, a.z, s0); s0 = fmaf(q.w, a.w, s0);
                    s1 = fmaf(q.x, c.x, s1); s1 = fmaf(q.y, c.y, s1);
                    s1 = fmaf(q.z, c.z, s1); s1 = fmaf(q.w, c.w, s1);
                }
                w0 = s0 + __shfl_xor(s0, 1) + ds * uu0;
                w1 = s1 + __shfl_xor(s1, 1) + ds * uu1;
            }
            {
                float d0 = uu0 * w0, d1 = uu1 * w1;
#pragma unroll
                for (int o = 32; o; o >>= 1) { d0 += __shfl_xor(d0, o); d1 += __shfl_xor(d1, o); }
                if (lane == 0) { scal[16 + w] = 0.5f * d0; scal[20 + w] = 0.5f * d1; }
            }
            __syncthreads();                                // BA
            // S2: uniform alpha/beta; update state; next gamma partials
            {
                const float g0 = scal[gb] + scal[gb + 1] + scal[gb + 2] + scal[gb + 3];
                const float g1 = scal[gb + 4] + scal[gb + 5] + scal[gb + 6] + scal[gb + 7];
                const float d0 = scal[16] + scal[17] + scal[18] + scal[19];
                const float d1 = scal[20] + scal[21] + scal[22] + scal[23];
                float be0, be1, al0, al1;
                if (k == 0) {
                    be0 = 0.0f; be1 = 0.0f;
                    al0 = (g0 > 1e-30f) ? g0 / d0 : 0.0f;
                    al1 = (g1 > 1e-30f) ? g1 / d1 : 0.0f;
                } else {
                    be0 = (g0old > 1e-30f) ? g0 / g0old : 0.0f;
                    be1 = (g1old > 1e-30f) ? g1 / g1old : 0.0f;
                    const float den0 = d0 - be0 * g0 / a0old;
                    const float den1 = d1 - be1 * g1 / a1old;
                    al0 = (g0 > 1e-30f && den0 > 1e-30f) ? g0 / den0 : 0.0f;
                    al1 = (g1 > 1e-30f && den1 > 1e-30f) ? g1 / den1 : 0.0f;
                }
                g0old = g0; g1old = g1;
                a0old = (al0 != 0.0f) ? al0 : 1.0f;
                a1old = (al1 != 0.0f) ? al1 : 1.0f;
                p0r = uu0 + be0 * p0r;  s0r = w0 + be0 * s0r;
                p1r = uu1 + be1 * p1r;  s1r = w1 + be1 * s1r;
                x0 += al0 * p0r;        r0 -= al0 * s0r;
                x1 += al1 * p1r;        r1 -= al1 * s1r;
                uu0 = dinv * r0;        uu1 = dinv * r1;
                if (h == 0) { u0[wr] = uu0; u1[wr] = uu1; }
                float ng0 = r0 * uu0, ng1 = r1 * uu1;
#pragma unroll
                for (int o = 32; o; o >>= 1) { ng0 += __shfl_xor(ng0, o); ng1 += __shfl_xor(ng1, o); }
                if (lane == 0) { scal[gn + w] = 0.5f * ng0; scal[gn + 4 + w] = 0.5f * ng1; }
            }
            __syncthreads();                                // BB
        }

        // ---- epilogue: dnu, step length, update ----
        {
            float sx0 = x0, sx1 = x1;
#pragma unroll
            for (int o = 32; o; o >>= 1) { sx0 += __shfl_xor(sx0, o); sx1 += __shfl_xor(sx1, o); }
            if (lane == 0) { scal[0 + w] = 0.5f * sx0; scal[4 + w] = 0.5f * sx1; }
        }
        __syncthreads();                                    // B4
        const float dnu = (scal[0] + scal[1] + scal[2] + scal[3] + r_pri)
                        / (scal[4] + scal[5] + scal[6] + scal[7]);
        const float da = x0 - dnu * x1;
        const float dl = -lmr + SIGMA_C * mu / avr - lmr * da / avr;
        {
            float rmin = 3.4e38f;
            if (da < 0.0f) rmin = fminf(rmin, -avr / da);
            if (dl < 0.0f) rmin = fminf(rmin, -lmr / dl);
#pragma unroll
            for (int o = 32; o; o >>= 1) rmin = fminf(rmin, __shfl_xor(rmin, o));
            if (lane == 0) scal[16 + w] = rmin;
        }
        __syncthreads();                                    // B5
        const float ts = fminf(1.0f, 0.99f * fminf(fminf(scal[16], scal[17]),
                                                   fminf(scal[18], scal[19])));
        nu  += ts * dnu;
        avr += ts * da;
        lmr += ts * dl;
        if (h == 0) avl[wr] = avr;
        __syncthreads();                                    // B6
    }

    if (h == 0) alphas[(size_t)b * N + r] = avr;
}

// ---------------- Kernel C: centers = alpha^T X ----------------
__global__ __launch_bounds__(256) void centers_kernel(const float* __restrict__ X,
                                                      const float* __restrict__ alphas,
                                                      float* __restrict__ out) {
    const int b = blockIdx.x;
    __shared__ float al[N];
    const int t = threadIdx.x;
    if (t < N) al[t] = alphas[(size_t)b * N + t];
    __syncthreads();
    const float* Xb = X + (size_t)b * N * DDIM;
    float acc0 = 0.0f, acc1 = 0.0f, acc2 = 0.0f, acc3 = 0.0f;
    for (int s = 0; s < N; ++s) {
        const float a = al[s];
        const float* row = Xb + (size_t)s * DDIM + t;
        acc0 += a * row[0];
        acc1 += a * row[256];
        acc2 += a * row[512];
        acc3 += a * row[768];
    }
    float* ob = out + (size_t)b * DDIM + t;
    ob[0]   = acc0;
    ob[256] = acc1;
    ob[512] = acc2;
    ob[768] = acc3;
}

extern "C" void kernel_launch(void* const* d_in, const int* in_sizes, int n_in,
                              void* d_out, int out_size, void* d_ws, size_t ws_size,
                              hipStream_t stream) {
    (void)in_sizes; (void)n_in; (void)out_size; (void)ws_size;
    const float* X = (const float*)d_in[0];
    float* out = (float*)d_out;
    float* Q = (float*)d_ws;                       // 512*128*128 f32 = 32 MB
    float* alphas = Q + (size_t)BATCH * N * N;     // + 256 KB
    gram_kernel<<<dim3(BATCH), dim3(256), 0, stream>>>(X, Q);
    ipm_cg<<<dim3(BATCH), dim3(256), 0, stream>>>(Q, alphas);
    centers_kernel<<<dim3(BATCH), dim3(256), 0, stream>>>(X, alphas, out);
}